// Round 4
// baseline (753.418 us; speedup 1.0000x reference)
//
#include <hip/hip_runtime.h>
#include <hip/hip_bf16.h>

typedef unsigned short u16;
typedef unsigned int   u32;
typedef _Float16 half2_t __attribute__((ext_vector_type(2)));
typedef short    bf16x8 __attribute__((ext_vector_type(8)));
typedef float    f32x4  __attribute__((ext_vector_type(4)));
typedef u32      u32x4v __attribute__((ext_vector_type(4)));

// Problem dims: B=128, T=512, V=50000, NT=24, E=128, H=256, Hd=128
#define TT   512

__device__ __forceinline__ float sigf(float x)  { return 1.0f / (1.0f + __expf(-x)); }
__device__ __forceinline__ float tanhf_(float x){ return 1.0f - 2.0f / (__expf(2.0f * x) + 1.0f); }

__device__ __forceinline__ u16 f2bf(float x) {
  __hip_bfloat16 h = __float2bfloat16(x);
  return *reinterpret_cast<u16*>(&h);
}
__device__ __forceinline__ float bf2f(u16 u) { return __uint_as_float(((u32)u) << 16); }
__device__ __forceinline__ u32 pk2(float a, float b) {
  return (u32)f2bf(a) | ((u32)f2bf(b) << 16);
}
__device__ __forceinline__ u16 f2h(float x) {
  _Float16 h = (_Float16)x;
  union { _Float16 f; u16 u; } c; c.f = h; return c.u;
}
__device__ __forceinline__ half2_t u2h2(u32 v) {
  union { u32 u; half2_t h; } c; c.u = v; return c.h;
}

// ---------------------------------------------------------------------------
// K0: weight prep. Wb bf16 [1024][128]; Whh16 f16x2 [2][512][64];
// bias f32 [1024]; Wout16 f16x2 [24][128].
// ---------------------------------------------------------------------------
__global__ __launch_bounds__(256) void prep_k(
    const float* __restrict__ Wih_f, const float* __restrict__ Wih_b,
    const float* __restrict__ Whh_f, const float* __restrict__ Whh_b,
    const float* __restrict__ bih_f, const float* __restrict__ bhh_f,
    const float* __restrict__ bih_b, const float* __restrict__ bhh_b,
    const float* __restrict__ W_out,
    u16* __restrict__ Wb, u32* __restrict__ Whh16, float* __restrict__ bias,
    u32* __restrict__ Wout16)
{
  int i = blockIdx.x * 256 + threadIdx.x;   // 131072 threads
  {
    int n = i >> 7, k = i & 127;
    float v = (n < 512) ? Wih_f[n * 128 + k] : Wih_b[(n - 512) * 128 + k];
    Wb[i] = f2bf(v);
  }
  if (i < 65536) {
    int d = i >> 15, rem = i & 32767, r = rem >> 6, kp = rem & 63;
    const float* W = d ? Whh_b : Whh_f;
    float f0 = W[r * 128 + 2 * kp], f1 = W[r * 128 + 2 * kp + 1];
    Whh16[i] = (u32)f2h(f0) | ((u32)f2h(f1) << 16);
  }
  if (i < 1024) {
    int d = i >> 9, jj = i & 511;
    bias[i] = d ? (bih_b[jj] + bhh_b[jj]) : (bih_f[jj] + bhh_f[jj]);
  }
  if (i < 3072) {
    Wout16[i] = (u32)f2h(W_out[2 * i]) | ((u32)f2h(W_out[2 * i + 1]) << 16);
  }
}

// ---------------------------------------------------------------------------
// K1: embedding gather -> bf16 xe [65536][128]
// ---------------------------------------------------------------------------
__global__ __launch_bounds__(256) void embed_k(
    const int* __restrict__ x, const float* __restrict__ emb, u16* __restrict__ xe)
{
  const int tid = threadIdx.x;
  const int r = blockIdx.x * 8 + (tid >> 5);
  const int lane = tid & 31;
  int token = x[r];
  float4 v = *(const float4*)&emb[(size_t)token * 128 + lane * 4];
  uint2 p; p.x = pk2(v.x, v.y); p.y = pk2(v.z, v.w);
  *(uint2*)&xe[(size_t)r * 128 + lane * 4] = p;
}

// ---------------------------------------------------------------------------
// K2: gates GEMM via bf16 MFMA 16x16x32.  G[m][n] = sum_k xe[m][k]*Wb[n][k]+bias[n]
// ---------------------------------------------------------------------------
__global__ __launch_bounds__(256, 2) void gates_mfma_k(
    const u16* __restrict__ xe, const u16* __restrict__ Wb,
    const float* __restrict__ bias, u16* __restrict__ Gout)
{
  const int tid = threadIdx.x;
  const int wid = tid >> 6, l = tid & 63;
  const int wm = wid >> 1, wn = wid & 1;
  const int M0 = blockIdx.y * 128, N0 = blockIdx.x * 128;
  const int lr = l & 15, lk = l >> 4;

  f32x4 acc[4][4];
#pragma unroll
  for (int i = 0; i < 4; ++i)
#pragma unroll
    for (int j = 0; j < 4; ++j) acc[i][j] = (f32x4){0.f, 0.f, 0.f, 0.f};

#pragma unroll
  for (int ks = 0; ks < 4; ++ks) {
    bf16x8 a[4], b[4];
#pragma unroll
    for (int mi = 0; mi < 4; ++mi)
      a[mi] = *(const bf16x8*)&xe[(size_t)(M0 + wm * 64 + mi * 16 + lr) * 128 + ks * 32 + lk * 8];
#pragma unroll
    for (int ni = 0; ni < 4; ++ni)
      b[ni] = *(const bf16x8*)&Wb[(size_t)(N0 + wn * 64 + ni * 16 + lr) * 128 + ks * 32 + lk * 8];
#pragma unroll
    for (int mi = 0; mi < 4; ++mi)
#pragma unroll
      for (int ni = 0; ni < 4; ++ni)
        acc[mi][ni] = __builtin_amdgcn_mfma_f32_16x16x32_bf16(a[mi], b[ni], acc[mi][ni], 0, 0, 0);
  }

  float bcol[4];
#pragma unroll
  for (int ni = 0; ni < 4; ++ni) bcol[ni] = bias[N0 + wn * 64 + ni * 16 + lr];

  __shared__ u16 cs[128][136];
#pragma unroll
  for (int mi = 0; mi < 4; ++mi)
#pragma unroll
    for (int ni = 0; ni < 4; ++ni) {
      int col = wn * 64 + ni * 16 + lr;
#pragma unroll
      for (int r = 0; r < 4; ++r) {
        int row = wm * 64 + mi * 16 + lk * 4 + r;
        cs[row][col] = f2bf(acc[mi][ni][r] + bcol[ni]);
      }
    }
  __syncthreads();
  {
    int row = tid >> 1, c0 = (tid & 1) * 64;
    u16* dst = &Gout[(size_t)(M0 + row) * 1024 + N0 + c0];
#pragma unroll
    for (int q = 0; q < 8; ++q)
      *(uint4*)&dst[q * 8] = *(const uint4*)&cs[row][c0 + q * 8];
  }
}

// ---------------------------------------------------------------------------
// K3: LSTM recurrence. 256 blocks (dir,sample) x 256 threads.
// Thread (r,hi) owns gate rows: hi=0 -> (i_r, f_r), hi=1 -> (g_r, o_r).
// Weights in 32 named u32x4 registers, pinned INSIDE the loop so the
// compiler cannot rematerialize the loads per step. G prefetch 2 deep.
// ---------------------------------------------------------------------------
__global__ __launch_bounds__(256, 1) void lstm_k(
    const u16* __restrict__ G, const u32* __restrict__ Whh16,
    u16* __restrict__ Hout)
{
  const int bid = blockIdx.x;
  const int dir = bid >> 7, b = bid & 127;
  const int tid = threadIdx.x;
  const int r   = tid & 127;
  const int hi  = tid >> 7;          // wave-uniform (waves 0,1 vs 2,3)
  const int g0  = r + hi * 256;      // i_r or g_r
  const int g1  = g0 + 128;          // f_r or o_r

  const u32* w0p = Whh16 + ((size_t)dir << 15) + (size_t)g0 * 64;
  const u32* w1p = Whh16 + ((size_t)dir << 15) + (size_t)g1 * 64;

#define LDQ(n) u32x4v q##n = *(const u32x4v*)(w0p + 4*(n)); \
               u32x4v p##n = *(const u32x4v*)(w1p + 4*(n));
  LDQ(0)  LDQ(1)  LDQ(2)  LDQ(3)  LDQ(4)  LDQ(5)  LDQ(6)  LDQ(7)
  LDQ(8)  LDQ(9)  LDQ(10) LDQ(11) LDQ(12) LDQ(13) LDQ(14) LDQ(15)
#undef LDQ

  __shared__ __align__(16) u32 hs2[64];   // h as 128 f16
  __shared__ float gact[512];
  if (tid < 64) hs2[tid] = 0u;
  float c = 0.0f;
  __syncthreads();

  const u16* gp = G + (size_t)b * TT * 1024 + (size_t)dir * 512;
  int t = dir ? (TT - 1) : 0;
  const int ts = dir ? -1 : 1;
  u16 cur0 = gp[(size_t)t * 1024 + g0];
  u16 cur1 = gp[(size_t)t * 1024 + g1];
  u16 nxt0 = gp[(size_t)(t + ts) * 1024 + g0];
  u16 nxt1 = gp[(size_t)(t + ts) * 1024 + g1];

  for (int step = 0; step < TT; ++step) {
    u16 pf0 = 0, pf1 = 0;
    if (step + 2 < TT) {
      pf0 = gp[(size_t)(t + 2 * ts) * 1024 + g0];
      pf1 = gp[(size_t)(t + 2 * ts) * 1024 + g1];
    }
    float gpre0 = bf2f(cur0), gpre1 = bf2f(cur1);

    float a00 = 0.f, a01 = 0.f, a10 = 0.f, a11 = 0.f;
    const u32x4v* h4 = (const u32x4v*)hs2;
#define DOT(n) { u32x4v hv = h4[n]; \
    a00 = __builtin_amdgcn_fdot2(u2h2(hv.x), u2h2(q##n.x), a00, false); \
    a00 = __builtin_amdgcn_fdot2(u2h2(hv.y), u2h2(q##n.y), a00, false); \
    a01 = __builtin_amdgcn_fdot2(u2h2(hv.z), u2h2(q##n.z), a01, false); \
    a01 = __builtin_amdgcn_fdot2(u2h2(hv.w), u2h2(q##n.w), a01, false); \
    a10 = __builtin_amdgcn_fdot2(u2h2(hv.x), u2h2(p##n.x), a10, false); \
    a10 = __builtin_amdgcn_fdot2(u2h2(hv.y), u2h2(p##n.y), a10, false); \
    a11 = __builtin_amdgcn_fdot2(u2h2(hv.z), u2h2(p##n.z), a11, false); \
    a11 = __builtin_amdgcn_fdot2(u2h2(hv.w), u2h2(p##n.w), a11, false); }
    DOT(0)  DOT(1)  DOT(2)  DOT(3)  DOT(4)  DOT(5)  DOT(6)  DOT(7)
    DOT(8)  DOT(9)  DOT(10) DOT(11) DOT(12) DOT(13) DOT(14) DOT(15)
#undef DOT

    // In-loop pin: mark every weight vector as live+modified each iteration
    // so the compiler must keep them resident in VGPRs across the loop.
#define PIN(a,b,c,d) asm volatile("" : "+v"(a), "+v"(b), "+v"(c), "+v"(d));
    PIN(q0,q1,q2,q3)   PIN(q4,q5,q6,q7)   PIN(q8,q9,q10,q11)   PIN(q12,q13,q14,q15)
    PIN(p0,p1,p2,p3)   PIN(p4,p5,p6,p7)   PIN(p8,p9,p10,p11)   PIN(p12,p13,p14,p15)
#undef PIN

    float v0 = gpre0 + a00 + a01;
    float v1 = gpre1 + a10 + a11;

    float act0, act1;
    if (hi == 0) { act0 = sigf(v0);   act1 = sigf(v1); }   // i, f
    else         { act0 = tanhf_(v0); act1 = sigf(v1); }   // g, o
    gact[g0] = act0; gact[g1] = act1;
    __syncthreads();
    if (hi == 0) {
      float iv = gact[r], fv = gact[128 + r], gv = gact[256 + r], ov = gact[384 + r];
      c = fv * c + iv * gv;
      float hvv = ov * tanhf_(c);
      ((u16*)hs2)[r] = f2h(hvv);
      Hout[((size_t)(b * TT + t)) * 256 + dir * 128 + r] = f2h(hvv);
    }
    __syncthreads();
    cur0 = nxt0; cur1 = nxt1; nxt0 = pf0; nxt1 = pf1;
    t += ts;
  }
}

// ---------------------------------------------------------------------------
// K4: emissions = h @ W_out^T + b_out.  H f16, W_out f16-packed in LDS, fdot2.
// ---------------------------------------------------------------------------
__global__ __launch_bounds__(256) void emis_k(
    const u16* __restrict__ Hb, const u32* __restrict__ Wout16,
    const float* __restrict__ b_out, float* __restrict__ em)
{
  __shared__ __align__(16) u32 wl2[24 * 128];   // 12 KB
  __shared__ float bo[24];
  const int tid = threadIdx.x;
  for (int i = tid; i < 3072; i += 256) wl2[i] = Wout16[i];
  if (tid < 24) bo[tid] = b_out[tid];
  __syncthreads();

  const int m = blockIdx.x * 256 + tid;
  float acc[24];
#pragma unroll
  for (int tg = 0; tg < 24; ++tg) acc[tg] = bo[tg];

  const u32* h2 = (const u32*)(Hb + (size_t)m * 256);
  for (int ck = 0; ck < 16; ++ck) {          // 8 f16 per chunk
    uint4 hv = *(const uint4*)(h2 + ck * 4);
#pragma unroll
    for (int tg = 0; tg < 24; ++tg) {
      u32x4v wv = *(const u32x4v*)&wl2[tg * 128 + ck * 4];
      float a = acc[tg];
      a = __builtin_amdgcn_fdot2(u2h2(hv.x), u2h2(wv.x), a, false);
      a = __builtin_amdgcn_fdot2(u2h2(hv.y), u2h2(wv.y), a, false);
      a = __builtin_amdgcn_fdot2(u2h2(hv.z), u2h2(wv.z), a, false);
      a = __builtin_amdgcn_fdot2(u2h2(hv.w), u2h2(wv.w), a, false);
      acc[tg] = a;
    }
  }
#pragma unroll
  for (int t6 = 0; t6 < 6; ++t6) {
    float4 o;
    o.x = acc[t6*4+0]; o.y = acc[t6*4+1]; o.z = acc[t6*4+2]; o.w = acc[t6*4+3];
    *(float4*)&em[(size_t)m * 24 + t6 * 4] = o;
  }
}

// ---------------------------------------------------------------------------
// K5: CRF forward scan + gold score + mean. One wave per sample, all-register:
// sc lives in lane j; sc_i broadcast via __shfl (readlane); transition column
// held in 12 VGPRs per lane; 24-wide logsumexp split across lane pairs
// (lanes 0..23: i=0..11, lanes 24..47: i=12..23). No LDS, no barriers.
// ---------------------------------------------------------------------------
__device__ __forceinline__ int get_mask(const void* mp, int idx, bool byte_mode) {
  return byte_mode ? (int)((const unsigned char*)mp)[idx] : ((const int*)mp)[idx];
}

__global__ __launch_bounds__(64) void crf_k(
    const float* __restrict__ em, const int* __restrict__ tags,
    const void* __restrict__ maskp, const float* __restrict__ trans,
    const float* __restrict__ start_tr, const float* __restrict__ end_tr,
    float* __restrict__ out)
{
  const int b = blockIdx.x;
  const int tid = threadIdx.x;
  const bool byte_mode = (*(const u32*)maskp != 1u);

  // sequence length (mask is a monotone prefix)
  int cnt = 0;
  for (int t = tid; t < TT; t += 64) cnt += get_mask(maskp, b * TT + t, byte_mode);
#pragma unroll
  for (int off = 32; off > 0; off >>= 1) cnt += __shfl_down(cnt, off);
  cnt = __shfl(cnt, 0);

  const bool act = (tid < 48);
  const int j  = (tid < 24) ? tid : tid - 24;     // column this lane computes
  const int i0 = (tid < 24) ? 0 : 12;             // i-range start
  const int partner = (tid < 24) ? tid + 24 : tid - 24;

  float tr_reg[12];
  if (act) {
#pragma unroll
    for (int k = 0; k < 12; ++k) tr_reg[k] = trans[(i0 + k) * 24 + j];
  }

  float sc = 0.f;
  if (act) sc = start_tr[j] + em[(size_t)(b * TT) * 24 + j];
  float em_next = 0.f;
  if (act && cnt > 1) em_next = em[(size_t)(b * TT + 1) * 24 + j];

  for (int t = 1; t < cnt; ++t) {
    float em_cur = em_next;
    if (act && t + 1 < cnt) em_next = em[(size_t)(b * TT + t + 1) * 24 + j];

    float v[12];
#pragma unroll
    for (int k = 0; k < 12; ++k) v[k] = __shfl(sc, i0 + k) + tr_reg[k];
    float mx = fmaxf(fmaxf(fmaxf(v[0], v[1]), fmaxf(v[2], v[3])),
                     fmaxf(fmaxf(v[4], v[5]), fmaxf(v[6], v[7])));
    mx = fmaxf(mx, fmaxf(fmaxf(v[8], v[9]), fmaxf(v[10], v[11])));
    float s = 0.f;
#pragma unroll
    for (int k = 0; k < 12; ++k) s += __expf(v[k] - mx);
    float mo = __shfl(mx, partner), so = __shfl(s, partner);
    float M = fmaxf(mx, mo);
    s = s * __expf(mx - M) + so * __expf(mo - M);
    sc = act ? (em_cur + M + __logf(s)) : 0.f;
  }

  // logZ = logsumexp over lanes 0..23 of sc + end_tr
  float z = (tid < 24) ? sc + end_tr[tid] : -1e30f;
  float zm = z;
#pragma unroll
  for (int off = 32; off > 0; off >>= 1) zm = fmaxf(zm, __shfl_xor(zm, off));
  float ze = (tid < 24) ? __expf(z - zm) : 0.f;
#pragma unroll
  for (int off = 32; off > 0; off >>= 1) ze += __shfl_xor(ze, off);
  float lzv = zm + __logf(ze);

  // gold score
  float part = 0.f;
  for (int t = tid; t < TT; t += 64) {
    if (t >= 1 && t < cnt) {
      int tp = tags[b * TT + t - 1], tc = tags[b * TT + t];
      part += trans[tp * 24 + tc] + em[((size_t)(b * TT + t)) * 24 + tc];
    }
  }
#pragma unroll
  for (int off = 32; off > 0; off >>= 1) part += __shfl_down(part, off);
  if (tid == 0) {
    int t0g = tags[b * TT];
    float gold = start_tr[t0g] + em[(size_t)(b * TT) * 24 + t0g] + part;
    gold += end_tr[tags[b * TT + cnt - 1]];
    atomicAdd(out, (lzv - gold) * (1.0f / 128.0f));
  }
}

// ---------------------------------------------------------------------------
extern "C" void kernel_launch(void* const* d_in, const int* in_sizes, int n_in,
                              void* d_out, int out_size, void* d_ws, size_t ws_size,
                              hipStream_t stream) {
  const int*   x     = (const int*)d_in[0];
  const int*   tags  = (const int*)d_in[1];
  const void*  mask  = d_in[2];
  const float* emb   = (const float*)d_in[3];
  const float* Wih_f = (const float*)d_in[4];
  const float* Whh_f = (const float*)d_in[5];
  const float* bih_f = (const float*)d_in[6];
  const float* bhh_f = (const float*)d_in[7];
  const float* Wih_b = (const float*)d_in[8];
  const float* Whh_b = (const float*)d_in[9];
  const float* bih_b = (const float*)d_in[10];
  const float* bhh_b = (const float*)d_in[11];
  const float* W_out = (const float*)d_in[12];
  const float* b_out = (const float*)d_in[13];
  const float* trans = (const float*)d_in[14];
  const float* st_tr = (const float*)d_in[15];
  const float* en_tr = (const float*)d_in[16];

  u16*   Gb     = (u16*)d_ws;                              // [65536][1024] bf16
  u16*   Hb     = Gb + (size_t)65536 * 1024;               // [65536][256]  f16
  float* em     = (float*)(Hb + (size_t)65536 * 256);      // [65536][24]   f32
  float* bias   = em + (size_t)65536 * 24;                 // [1024]
  u16*   Wb     = (u16*)(bias + 1024);                     // [1024][128]   bf16
  u32*   Whh16  = (u32*)(Wb + 131072);                     // [2][512][64]  f16x2
  u32*   Wout16 = Whh16 + 65536;                           // [24][128]     f16x2
  u16*   xe     = Hb;  // alias: xe dead before lstm_k writes Hb

  prep_k<<<512, 256, 0, stream>>>(Wih_f, Wih_b, Whh_f, Whh_b,
                                  bih_f, bhh_f, bih_b, bhh_b, W_out,
                                  Wb, Whh16, bias, Wout16);
  embed_k<<<8192, 256, 0, stream>>>(x, emb, xe);
  gates_mfma_k<<<dim3(8, 512), 256, 0, stream>>>(xe, Wb, bias, Gb);
  lstm_k<<<256, 256, 0, stream>>>(Gb, Whh16, Hb);
  emis_k<<<256, 256, 0, stream>>>(Hb, Wout16, b_out, em);
  hipMemsetAsync(d_out, 0, sizeof(float), stream);
  crf_k<<<128, 64, 0, stream>>>(em, tags, mask, trans, st_tr, en_tr, (float*)d_out);
}

// Round 5
// 694.766 us; speedup vs baseline: 1.0844x; 1.0844x over previous
//
#include <hip/hip_runtime.h>
#include <hip/hip_bf16.h>

typedef unsigned short u16;
typedef unsigned int   u32;
typedef _Float16 half2_t __attribute__((ext_vector_type(2)));
typedef short    bf16x8 __attribute__((ext_vector_type(8)));
typedef float    f32x4  __attribute__((ext_vector_type(4)));
typedef u32      u32x4v __attribute__((ext_vector_type(4)));

// Problem dims: B=128, T=512, V=50000, NT=24, E=128, H=256, Hd=128
#define TT   512

__device__ __forceinline__ float sigf(float x)  { return 1.0f / (1.0f + __expf(-x)); }
__device__ __forceinline__ float tanhf_(float x){ return 1.0f - 2.0f / (__expf(2.0f * x) + 1.0f); }

__device__ __forceinline__ u16 f2bf(float x) {
  __hip_bfloat16 h = __float2bfloat16(x);
  return *reinterpret_cast<u16*>(&h);
}
__device__ __forceinline__ float bf2f(u16 u) { return __uint_as_float(((u32)u) << 16); }
__device__ __forceinline__ u32 pk2(float a, float b) {
  return (u32)f2bf(a) | ((u32)f2bf(b) << 16);
}
__device__ __forceinline__ u16 f2h(float x) {
  _Float16 h = (_Float16)x;
  union { _Float16 f; u16 u; } c; c.f = h; return c.u;
}
__device__ __forceinline__ half2_t u2h2(u32 v) {
  union { u32 u; half2_t h; } c; c.u = v; return c.h;
}

// ---------------------------------------------------------------------------
// K0: weight prep. Wb bf16 [1024][128]; Whh16 f16x2 [2][512][64];
// bias f32 [1024]; Wout16 f16x2 [24][128].
// ---------------------------------------------------------------------------
__global__ __launch_bounds__(256) void prep_k(
    const float* __restrict__ Wih_f, const float* __restrict__ Wih_b,
    const float* __restrict__ Whh_f, const float* __restrict__ Whh_b,
    const float* __restrict__ bih_f, const float* __restrict__ bhh_f,
    const float* __restrict__ bih_b, const float* __restrict__ bhh_b,
    const float* __restrict__ W_out,
    u16* __restrict__ Wb, u32* __restrict__ Whh16, float* __restrict__ bias,
    u32* __restrict__ Wout16)
{
  int i = blockIdx.x * 256 + threadIdx.x;   // 131072 threads
  {
    int n = i >> 7, k = i & 127;
    float v = (n < 512) ? Wih_f[n * 128 + k] : Wih_b[(n - 512) * 128 + k];
    Wb[i] = f2bf(v);
  }
  if (i < 65536) {
    int d = i >> 15, rem = i & 32767, r = rem >> 6, kp = rem & 63;
    const float* W = d ? Whh_b : Whh_f;
    float f0 = W[r * 128 + 2 * kp], f1 = W[r * 128 + 2 * kp + 1];
    Whh16[i] = (u32)f2h(f0) | ((u32)f2h(f1) << 16);
  }
  if (i < 1024) {
    int d = i >> 9, jj = i & 511;
    bias[i] = d ? (bih_b[jj] + bhh_b[jj]) : (bih_f[jj] + bhh_f[jj]);
  }
  if (i < 3072) {
    Wout16[i] = (u32)f2h(W_out[2 * i]) | ((u32)f2h(W_out[2 * i + 1]) << 16);
  }
}

// ---------------------------------------------------------------------------
// K1: embedding gather -> bf16 xe [65536][128]
// ---------------------------------------------------------------------------
__global__ __launch_bounds__(256) void embed_k(
    const int* __restrict__ x, const float* __restrict__ emb, u16* __restrict__ xe)
{
  const int tid = threadIdx.x;
  const int r = blockIdx.x * 8 + (tid >> 5);
  const int lane = tid & 31;
  int token = x[r];
  float4 v = *(const float4*)&emb[(size_t)token * 128 + lane * 4];
  uint2 p; p.x = pk2(v.x, v.y); p.y = pk2(v.z, v.w);
  *(uint2*)&xe[(size_t)r * 128 + lane * 4] = p;
}

// ---------------------------------------------------------------------------
// K2: gates GEMM via bf16 MFMA 16x16x32.  G[m][n] = sum_k xe[m][k]*Wb[n][k]+bias[n]
// ---------------------------------------------------------------------------
__global__ __launch_bounds__(256, 2) void gates_mfma_k(
    const u16* __restrict__ xe, const u16* __restrict__ Wb,
    const float* __restrict__ bias, u16* __restrict__ Gout)
{
  const int tid = threadIdx.x;
  const int wid = tid >> 6, l = tid & 63;
  const int wm = wid >> 1, wn = wid & 1;
  const int M0 = blockIdx.y * 128, N0 = blockIdx.x * 128;
  const int lr = l & 15, lk = l >> 4;

  f32x4 acc[4][4];
#pragma unroll
  for (int i = 0; i < 4; ++i)
#pragma unroll
    for (int j = 0; j < 4; ++j) acc[i][j] = (f32x4){0.f, 0.f, 0.f, 0.f};

#pragma unroll
  for (int ks = 0; ks < 4; ++ks) {
    bf16x8 a[4], b[4];
#pragma unroll
    for (int mi = 0; mi < 4; ++mi)
      a[mi] = *(const bf16x8*)&xe[(size_t)(M0 + wm * 64 + mi * 16 + lr) * 128 + ks * 32 + lk * 8];
#pragma unroll
    for (int ni = 0; ni < 4; ++ni)
      b[ni] = *(const bf16x8*)&Wb[(size_t)(N0 + wn * 64 + ni * 16 + lr) * 128 + ks * 32 + lk * 8];
#pragma unroll
    for (int mi = 0; mi < 4; ++mi)
#pragma unroll
      for (int ni = 0; ni < 4; ++ni)
        acc[mi][ni] = __builtin_amdgcn_mfma_f32_16x16x32_bf16(a[mi], b[ni], acc[mi][ni], 0, 0, 0);
  }

  float bcol[4];
#pragma unroll
  for (int ni = 0; ni < 4; ++ni) bcol[ni] = bias[N0 + wn * 64 + ni * 16 + lr];

  __shared__ u16 cs[128][136];
#pragma unroll
  for (int mi = 0; mi < 4; ++mi)
#pragma unroll
    for (int ni = 0; ni < 4; ++ni) {
      int col = wn * 64 + ni * 16 + lr;
#pragma unroll
      for (int r = 0; r < 4; ++r) {
        int row = wm * 64 + mi * 16 + lk * 4 + r;
        cs[row][col] = f2bf(acc[mi][ni][r] + bcol[ni]);
      }
    }
  __syncthreads();
  {
    int row = tid >> 1, c0 = (tid & 1) * 64;
    u16* dst = &Gout[(size_t)(M0 + row) * 1024 + N0 + c0];
#pragma unroll
    for (int q = 0; q < 8; ++q)
      *(uint4*)&dst[q * 8] = *(const uint4*)&cs[row][c0 + q * 8];
  }
}

// ---------------------------------------------------------------------------
// K3: LSTM recurrence. 256 blocks (dir,sample) x 512 threads (8 waves =
// 2 waves/SIMD for latency hiding). Thread j owns ONE gate row: 64 u32
// f16-pair weights in 16 named u32x4 registers, pinned in-loop (residency
// proven in R4). h f16 in LDS (broadcast reads). c/h tail distributed:
// wave w lanes 0..15 own hidden units 16w..16w+15 so all 8 waves work.
// ---------------------------------------------------------------------------
__global__ __launch_bounds__(512, 1) void lstm_k(
    const u16* __restrict__ G, const u32* __restrict__ Whh16,
    u16* __restrict__ Hout)
{
  const int bid = blockIdx.x;
  const int dir = bid >> 7, b = bid & 127;
  const int j   = threadIdx.x;        // gate row 0..511
  const int w   = j >> 6, l = j & 63; // wave, lane
  const int u   = 16 * w + (l & 15);  // owned hidden unit (lanes 0..15 only)
  const int gate = j >> 7;            // 0=i 1=f 2=g 3=o (wave-uniform)

  const u32* wp = Whh16 + ((size_t)dir << 15) + (size_t)j * 64;
#define LDQ(n) u32x4v q##n = *(const u32x4v*)(wp + 4*(n));
  LDQ(0)  LDQ(1)  LDQ(2)  LDQ(3)  LDQ(4)  LDQ(5)  LDQ(6)  LDQ(7)
  LDQ(8)  LDQ(9)  LDQ(10) LDQ(11) LDQ(12) LDQ(13) LDQ(14) LDQ(15)
#undef LDQ

  __shared__ __align__(16) u32 hs2[64];   // h as 128 f16
  __shared__ float gact[512];
  if (j < 64) hs2[j] = 0u;
  float c = 0.0f;
  __syncthreads();

  const u16* gp = G + (size_t)b * TT * 1024 + (size_t)dir * 512;
  int t = dir ? (TT - 1) : 0;
  const int ts = dir ? -1 : 1;
  u16 cur = gp[(size_t)t * 1024 + j];
  u16 nxt = gp[(size_t)(t + ts) * 1024 + j];

  for (int step = 0; step < TT; ++step) {
    u16 pf = 0;
    if (step + 2 < TT) pf = gp[(size_t)(t + 2 * ts) * 1024 + j];
    float gpre = bf2f(cur);

    float a0 = 0.f, a1 = 0.f;
    const u32x4v* h4 = (const u32x4v*)hs2;
#define DOT(n) { u32x4v hv = h4[n]; \
    a0 = __builtin_amdgcn_fdot2(u2h2(hv.x), u2h2(q##n.x), a0, false); \
    a0 = __builtin_amdgcn_fdot2(u2h2(hv.y), u2h2(q##n.y), a0, false); \
    a1 = __builtin_amdgcn_fdot2(u2h2(hv.z), u2h2(q##n.z), a1, false); \
    a1 = __builtin_amdgcn_fdot2(u2h2(hv.w), u2h2(q##n.w), a1, false); }
    DOT(0)  DOT(1)  DOT(2)  DOT(3)  DOT(4)  DOT(5)  DOT(6)  DOT(7)
    DOT(8)  DOT(9)  DOT(10) DOT(11) DOT(12) DOT(13) DOT(14) DOT(15)
#undef DOT

    // In-loop pin: keep all 16 weight vectors VGPR-resident across the loop.
#define PIN(a,b,c,d) asm volatile("" : "+v"(a), "+v"(b), "+v"(c), "+v"(d));
    PIN(q0,q1,q2,q3)   PIN(q4,q5,q6,q7)   PIN(q8,q9,q10,q11)   PIN(q12,q13,q14,q15)
#undef PIN

    float v = gpre + a0 + a1;
    float a = (gate == 2) ? tanhf_(v) : sigf(v);
    gact[j] = a;
    __syncthreads();
    if ((l & 48) == 0) {   // lanes 0..15 of every wave: owned unit u
      float iv = gact[u], fv = gact[128 + u], gv = gact[256 + u], ov = gact[384 + u];
      c = fv * c + iv * gv;
      float hvv = ov * tanhf_(c);
      ((u16*)hs2)[u] = f2h(hvv);
      Hout[((size_t)(b * TT + t)) * 256 + dir * 128 + u] = f2h(hvv);
    }
    __syncthreads();
    cur = nxt; nxt = pf;
    t += ts;
  }
}

// ---------------------------------------------------------------------------
// K4: emissions = h @ W_out^T + b_out.  H f16, W_out f16-packed in LDS, fdot2.
// ---------------------------------------------------------------------------
__global__ __launch_bounds__(256) void emis_k(
    const u16* __restrict__ Hb, const u32* __restrict__ Wout16,
    const float* __restrict__ b_out, float* __restrict__ em)
{
  __shared__ __align__(16) u32 wl2[24 * 128];   // 12 KB
  __shared__ float bo[24];
  const int tid = threadIdx.x;
  for (int i = tid; i < 3072; i += 256) wl2[i] = Wout16[i];
  if (tid < 24) bo[tid] = b_out[tid];
  __syncthreads();

  const int m = blockIdx.x * 256 + tid;
  float acc[24];
#pragma unroll
  for (int tg = 0; tg < 24; ++tg) acc[tg] = bo[tg];

  const u32* h2 = (const u32*)(Hb + (size_t)m * 256);
  for (int ck = 0; ck < 16; ++ck) {          // 8 f16 per chunk
    uint4 hv = *(const uint4*)(h2 + ck * 4);
#pragma unroll
    for (int tg = 0; tg < 24; ++tg) {
      u32x4v wv = *(const u32x4v*)&wl2[tg * 128 + ck * 4];
      float a = acc[tg];
      a = __builtin_amdgcn_fdot2(u2h2(hv.x), u2h2(wv.x), a, false);
      a = __builtin_amdgcn_fdot2(u2h2(hv.y), u2h2(wv.y), a, false);
      a = __builtin_amdgcn_fdot2(u2h2(hv.z), u2h2(wv.z), a, false);
      a = __builtin_amdgcn_fdot2(u2h2(hv.w), u2h2(wv.w), a, false);
      acc[tg] = a;
    }
  }
#pragma unroll
  for (int t6 = 0; t6 < 6; ++t6) {
    float4 o;
    o.x = acc[t6*4+0]; o.y = acc[t6*4+1]; o.z = acc[t6*4+2]; o.w = acc[t6*4+3];
    *(float4*)&em[(size_t)m * 24 + t6 * 4] = o;
  }
}

// ---------------------------------------------------------------------------
// K5: CRF forward scan + gold score + mean. One wave per sample, all-register:
// sc in lane j; broadcasts via __shfl; logsumexp split across lane pairs.
// ---------------------------------------------------------------------------
__device__ __forceinline__ int get_mask(const void* mp, int idx, bool byte_mode) {
  return byte_mode ? (int)((const unsigned char*)mp)[idx] : ((const int*)mp)[idx];
}

__global__ __launch_bounds__(64) void crf_k(
    const float* __restrict__ em, const int* __restrict__ tags,
    const void* __restrict__ maskp, const float* __restrict__ trans,
    const float* __restrict__ start_tr, const float* __restrict__ end_tr,
    float* __restrict__ out)
{
  const int b = blockIdx.x;
  const int tid = threadIdx.x;
  const bool byte_mode = (*(const u32*)maskp != 1u);

  int cnt = 0;
  for (int t = tid; t < TT; t += 64) cnt += get_mask(maskp, b * TT + t, byte_mode);
#pragma unroll
  for (int off = 32; off > 0; off >>= 1) cnt += __shfl_down(cnt, off);
  cnt = __shfl(cnt, 0);

  const bool act = (tid < 48);
  const int j  = (tid < 24) ? tid : tid - 24;
  const int i0 = (tid < 24) ? 0 : 12;
  const int partner = (tid < 24) ? tid + 24 : tid - 24;

  float tr_reg[12];
  if (act) {
#pragma unroll
    for (int k = 0; k < 12; ++k) tr_reg[k] = trans[(i0 + k) * 24 + j];
  }

  float sc = 0.f;
  if (act) sc = start_tr[j] + em[(size_t)(b * TT) * 24 + j];
  float em_next = 0.f;
  if (act && cnt > 1) em_next = em[(size_t)(b * TT + 1) * 24 + j];

  for (int t = 1; t < cnt; ++t) {
    float em_cur = em_next;
    if (act && t + 1 < cnt) em_next = em[(size_t)(b * TT + t + 1) * 24 + j];

    float v[12];
#pragma unroll
    for (int k = 0; k < 12; ++k) v[k] = __shfl(sc, i0 + k) + tr_reg[k];
    float mx = fmaxf(fmaxf(fmaxf(v[0], v[1]), fmaxf(v[2], v[3])),
                     fmaxf(fmaxf(v[4], v[5]), fmaxf(v[6], v[7])));
    mx = fmaxf(mx, fmaxf(fmaxf(v[8], v[9]), fmaxf(v[10], v[11])));
    float s = 0.f;
#pragma unroll
    for (int k = 0; k < 12; ++k) s += __expf(v[k] - mx);
    float mo = __shfl(mx, partner), so = __shfl(s, partner);
    float M = fmaxf(mx, mo);
    s = s * __expf(mx - M) + so * __expf(mo - M);
    sc = act ? (em_cur + M + __logf(s)) : 0.f;
  }

  float z = (tid < 24) ? sc + end_tr[tid] : -1e30f;
  float zm = z;
#pragma unroll
  for (int off = 32; off > 0; off >>= 1) zm = fmaxf(zm, __shfl_xor(zm, off));
  float ze = (tid < 24) ? __expf(z - zm) : 0.f;
#pragma unroll
  for (int off = 32; off > 0; off >>= 1) ze += __shfl_xor(ze, off);
  float lzv = zm + __logf(ze);

  float part = 0.f;
  for (int t = tid; t < TT; t += 64) {
    if (t >= 1 && t < cnt) {
      int tp = tags[b * TT + t - 1], tc = tags[b * TT + t];
      part += trans[tp * 24 + tc] + em[((size_t)(b * TT + t)) * 24 + tc];
    }
  }
#pragma unroll
  for (int off = 32; off > 0; off >>= 1) part += __shfl_down(part, off);
  if (tid == 0) {
    int t0g = tags[b * TT];
    float gold = start_tr[t0g] + em[(size_t)(b * TT) * 24 + t0g] + part;
    gold += end_tr[tags[b * TT + cnt - 1]];
    atomicAdd(out, (lzv - gold) * (1.0f / 128.0f));
  }
}

// ---------------------------------------------------------------------------
extern "C" void kernel_launch(void* const* d_in, const int* in_sizes, int n_in,
                              void* d_out, int out_size, void* d_ws, size_t ws_size,
                              hipStream_t stream) {
  const int*   x     = (const int*)d_in[0];
  const int*   tags  = (const int*)d_in[1];
  const void*  mask  = d_in[2];
  const float* emb   = (const float*)d_in[3];
  const float* Wih_f = (const float*)d_in[4];
  const float* Whh_f = (const float*)d_in[5];
  const float* bih_f = (const float*)d_in[6];
  const float* bhh_f = (const float*)d_in[7];
  const float* Wih_b = (const float*)d_in[8];
  const float* Whh_b = (const float*)d_in[9];
  const float* bih_b = (const float*)d_in[10];
  const float* bhh_b = (const float*)d_in[11];
  const float* W_out = (const float*)d_in[12];
  const float* b_out = (const float*)d_in[13];
  const float* trans = (const float*)d_in[14];
  const float* st_tr = (const float*)d_in[15];
  const float* en_tr = (const float*)d_in[16];

  u16*   Gb     = (u16*)d_ws;                              // [65536][1024] bf16
  u16*   Hb     = Gb + (size_t)65536 * 1024;               // [65536][256]  f16
  float* em     = (float*)(Hb + (size_t)65536 * 256);      // [65536][24]   f32
  float* bias   = em + (size_t)65536 * 24;                 // [1024]
  u16*   Wb     = (u16*)(bias + 1024);                     // [1024][128]   bf16
  u32*   Whh16  = (u32*)(Wb + 131072);                     // [2][512][64]  f16x2
  u32*   Wout16 = Whh16 + 65536;                           // [24][128]     f16x2
  u16*   xe     = Hb;  // alias: xe dead before lstm_k writes Hb

  prep_k<<<512, 256, 0, stream>>>(Wih_f, Wih_b, Whh_f, Whh_b,
                                  bih_f, bhh_f, bih_b, bhh_b, W_out,
                                  Wb, Whh16, bias, Wout16);
  embed_k<<<8192, 256, 0, stream>>>(x, emb, xe);
  gates_mfma_k<<<dim3(8, 512), 256, 0, stream>>>(xe, Wb, bias, Gb);
  lstm_k<<<256, 512, 0, stream>>>(Gb, Whh16, Hb);
  emis_k<<<256, 256, 0, stream>>>(Hb, Wout16, b_out, em);
  hipMemsetAsync(d_out, 0, sizeof(float), stream);
  crf_k<<<128, 64, 0, stream>>>(em, tags, mask, trans, st_tr, en_tr, (float*)d_out);
}